// Round 1
// baseline (6341.574 us; speedup 1.0000x reference)
//
#include <hip/hip_runtime.h>
#include <math.h>

#define T_STEPS 16
#define NB 32
#define D_IN 256
#define D_HID 512
#define D_LAT 128

static __device__ __forceinline__ float gelu_f(float x){
  return 0.5f * x * (1.0f + erff(x * 0.70710678118654752440f));
}
static __device__ __forceinline__ float sigm_f(float x){
  return 1.0f / (1.0f + expf(-x));
}

// ---------------- precompute ----------------
__global__ void k_count(const int* __restrict__ dst, int E, int* __restrict__ counts){
  int e = blockIdx.x*256 + threadIdx.x;
  if (e < E) atomicAdd(&counts[dst[e]], 1);
}

__global__ void k_dinv(const int* __restrict__ counts, float* __restrict__ dinv, int n){
  int i = blockIdx.x*256 + threadIdx.x;
  if (i < n) dinv[i] = 1.0f / sqrtf((float)(counts[i] + 1));
}

__global__ void k_scan(const int* __restrict__ counts, int* __restrict__ row_ptr, int n){
  __shared__ int sm[1024];
  __shared__ int carry;
  if (threadIdx.x == 0) carry = 0;
  __syncthreads();
  for (int base = 0; base < n; base += 1024){
    int i = base + threadIdx.x;
    int v = (i < n) ? counts[i] : 0;
    sm[threadIdx.x] = v;
    __syncthreads();
    for (int off = 1; off < 1024; off <<= 1){
      int t = (threadIdx.x >= off) ? sm[threadIdx.x - off] : 0;
      __syncthreads();
      sm[threadIdx.x] += t;
      __syncthreads();
    }
    if (i < n) row_ptr[i] = carry + sm[threadIdx.x] - v;
    int total = sm[1023];
    __syncthreads();
    if (threadIdx.x == 0) carry += total;
    __syncthreads();
  }
  if (threadIdx.x == 0) row_ptr[n] = carry;
}

__global__ void k_place(const int* __restrict__ src, const int* __restrict__ dst,
                        const int* __restrict__ row_ptr, int* __restrict__ fill,
                        int* __restrict__ csr_col, int E){
  int e = blockIdx.x*256 + threadIdx.x;
  if (e < E){
    int d = dst[e];
    int p = row_ptr[d] + atomicAdd(&fill[d], 1);
    csr_col[p] = src[e];
  }
}

__global__ void k_ps_edges(const int* __restrict__ src, const int* __restrict__ dst,
                           const int* __restrict__ batch, const float* __restrict__ dinv,
                           float* __restrict__ ps, int E, int n){
  int e = blockIdx.x*256 + threadIdx.x;
  if (e < E){
    int s = src[e], d = dst[e];
    atomicAdd(&ps[(size_t)batch[d]*n + s], dinv[s]*dinv[d]);
  }
}

__global__ void k_ps_self(const int* __restrict__ batch, const float* __restrict__ dinv,
                          float* __restrict__ ps, float* __restrict__ cntb, int n){
  int i = blockIdx.x*256 + threadIdx.x;
  if (i < n){
    ps[(size_t)batch[i]*n + i] += dinv[i]*dinv[i];
    atomicAdd(&cntb[batch[i]], 1.0f);
  }
}

// ---------------- GCN ----------------
// sx = S @ x_t  (one wave per dst row, float4 across the 256-wide row)
__global__ __launch_bounds__(256) void k_spmm(const float* __restrict__ x, const float* __restrict__ dinv,
                       const int* __restrict__ row_ptr, const int* __restrict__ csr_col,
                       float* __restrict__ sx, int n){
  int i = blockIdx.x*4 + (threadIdx.x >> 6);
  int lane = threadIdx.x & 63;
  if (i >= n) return;
  const float4* x4 = (const float4*)x;
  float di = dinv[i];
  float4 a = x4[(size_t)i*64 + lane];
  float4 acc = make_float4(di*a.x, di*a.y, di*a.z, di*a.w);
  int e0 = row_ptr[i], e1 = row_ptr[i+1];
  for (int e = e0; e < e1; ++e){
    int c = csr_col[e];
    float w = dinv[c];
    float4 v = x4[(size_t)c*64 + lane];
    acc.x += w*v.x; acc.y += w*v.y; acc.z += w*v.z; acc.w += w*v.w;
  }
  acc.x *= di; acc.y *= di; acc.z *= di; acc.w *= di;
  ((float4*)sx)[(size_t)i*64 + lane] = acc;
}

// h1 = gelu(sx @ W1 + b1)   sx: M x 256, W1: 256 x 512
__global__ __launch_bounds__(256) void k_gemm_gelu(const float* __restrict__ A, const float* __restrict__ B,
                            const float* __restrict__ bias, float* __restrict__ C, int M){
  __shared__ float As[32][68];   // [k][m], row stride 68*4=272B (16B multiple)
  __shared__ float Bs[32][64];   // [k][n]
  int bm = blockIdx.x * 64;
  int bn = blockIdx.y * 64;
  int tid = threadIdx.x;
  int tx = tid & 15, ty = tid >> 4;
  float acc[4][4] = {{0.f}};
  for (int k0 = 0; k0 < 256; k0 += 32){
    for (int s = tid; s < 512; s += 256){
      int row = s >> 3, c4 = s & 7;
      int gr = bm + row;
      float4 v = make_float4(0.f,0.f,0.f,0.f);
      if (gr < M) v = *(const float4*)(A + (size_t)gr*256 + k0 + c4*4);
      As[c4*4+0][row] = v.x; As[c4*4+1][row] = v.y; As[c4*4+2][row] = v.z; As[c4*4+3][row] = v.w;
    }
    for (int s = tid; s < 512; s += 256){
      int row = s >> 4, c4 = s & 15;
      *(float4*)(&Bs[row][c4*4]) = *(const float4*)(B + (size_t)(k0+row)*512 + bn + c4*4);
    }
    __syncthreads();
    #pragma unroll
    for (int kk = 0; kk < 32; ++kk){
      float4 av = *(const float4*)(&As[kk][ty*4]);
      float4 bv = *(const float4*)(&Bs[kk][tx*4]);
      float a[4] = {av.x, av.y, av.z, av.w};
      float b[4] = {bv.x, bv.y, bv.z, bv.w};
      #pragma unroll
      for (int i=0;i<4;++i)
        #pragma unroll
        for (int j=0;j<4;++j) acc[i][j] += a[i]*b[j];
    }
    __syncthreads();
  }
  #pragma unroll
  for (int i=0;i<4;++i){
    int row = bm + ty*4 + i;
    if (row < M){
      #pragma unroll
      for (int j=0;j<4;++j){
        int col = bn + tx*4 + j;
        C[(size_t)row*512 + col] = gelu_f(acc[i][j] + bias[col]);
      }
    }
  }
}

// pp += ps(32 x n) @ h1(n x 512), split-K with atomics
__global__ __launch_bounds__(256) void k_pool(const float* __restrict__ ps, const float* __restrict__ h1,
                       float* __restrict__ pp, int n){
  __shared__ float pss[32][65];
  int tid = threadIdx.x;
  int tx = tid & 127, ty = tid >> 7;
  int k0 = blockIdx.x * 512;
  int n0 = blockIdx.y * 128;
  float acc[16];
  #pragma unroll
  for (int m=0;m<16;++m) acc[m] = 0.f;
  for (int kc=0; kc<512; kc+=64){
    int kb = k0 + kc;
    for (int s=tid; s<2048; s+=256){
      int m = s >> 6, kk = s & 63;
      int gk = kb + kk;
      pss[m][kk] = (gk < n) ? ps[(size_t)m*n + gk] : 0.f;
    }
    __syncthreads();
    int kmax = n - kb; if (kmax > 64) kmax = 64; if (kmax < 0) kmax = 0;
    for (int kk=0; kk<kmax; ++kk){
      float hv = h1[(size_t)(kb+kk)*512 + n0 + tx];
      #pragma unroll
      for (int m=0;m<16;++m) acc[m] += pss[ty*16+m][kk]*hv;
    }
    __syncthreads();
  }
  #pragma unroll
  for (int m=0;m<16;++m) atomicAdd(&pp[(size_t)(ty*16+m)*512 + n0 + tx], acc[m]);
}

// seq[b][t][k] = sum_j pp[t][b][j]*W2[j][k] + cnt[b]*b2[k]
__global__ void k_seq(const float* __restrict__ pp_all, const float* __restrict__ W2,
                      const float* __restrict__ b2, const float* __restrict__ cntb,
                      float* __restrict__ seq){
  int g = blockIdx.x*256 + threadIdx.x;  // 512*512 outputs
  int k = g & 511;
  int bt = g >> 9;
  int b = bt >> 4, t = bt & 15;
  const float* pr = pp_all + (size_t)(t*NB + b)*512;
  float acc = cntb[b]*b2[k];
  for (int j=0;j<512;++j) acc += pr[j]*W2[(size_t)j*512+k];
  seq[g] = acc;
}

// ---------------- LSTM ----------------
__global__ void k_transpose(const float* __restrict__ in, float* __restrict__ out, int R, int C){
  __shared__ float tile[32][33];
  int c0 = blockIdx.x*32, r0 = blockIdx.y*32;
  int tx = threadIdx.x, ty = threadIdx.y;  // (32,8)
  for (int j=0;j<32;j+=8){
    tile[ty+j][tx] = in[(size_t)(r0+ty+j)*C + c0 + tx];
  }
  __syncthreads();
  for (int j=0;j<32;j+=8){
    out[(size_t)(c0+ty+j)*R + r0 + tx] = tile[tx][ty+j];
  }
}

// xg[bt][j] = bih[j]+bhh[j] + sum_k in[bt][k]*WT[k][j]
__global__ __launch_bounds__(256) void k_xg(const float* __restrict__ in, const float* __restrict__ WT,
                     const float* __restrict__ bih, const float* __restrict__ bhh,
                     float* __restrict__ xg){
  __shared__ float ins[8][512];
  int jg = blockIdx.x & 7, btg = blockIdx.x >> 3;
  int tid = threadIdx.x;
  int j = jg*256 + tid;
  const float4* in4 = (const float4*)(in + (size_t)btg*8*512);
  float4* ins4 = (float4*)ins;
  for (int s=tid; s<1024; s+=256) ins4[s] = in4[s];
  __syncthreads();
  float bb = bih[j] + bhh[j];
  float acc[8];
  #pragma unroll
  for (int r=0;r<8;++r) acc[r] = bb;
  for (int kk=0; kk<512; ++kk){
    float w = WT[(size_t)kk*2048 + j];
    #pragma unroll
    for (int r=0;r<8;++r) acc[r] += ins[r][kk]*w;
  }
  for (int r=0;r<8;++r) xg[(size_t)(btg*8+r)*2048 + j] = acc[r];
}

__global__ __launch_bounds__(256) void k_lstm_step(const float* __restrict__ xg, const float* __restrict__ WhhT,
                            const float* __restrict__ h_in, float* __restrict__ h_out,
                            float* __restrict__ c, float* __restrict__ ys, int t){
  __shared__ float hs[8][512];
  int kg = blockIdx.x & 15, bg = blockIdx.x >> 4;
  int tid = threadIdx.x;
  int tb = tid >> 5, tk = tid & 31;
  const float4* h4 = (const float4*)(h_in + (size_t)bg*8*512);
  float4* hs4 = (float4*)hs;
  for (int s=tid; s<1024; s+=256) hs4[s] = h4[s];
  __syncthreads();
  int b = bg*8 + tb;
  int k = kg*32 + tk;
  const float* xgr = xg + (size_t)(b*T_STEPS + t)*2048;
  float gi = xgr[k], gf = xgr[k+512], gg = xgr[k+1024], go = xgr[k+1536];
  for (int kk=0; kk<512; ++kk){
    float hv = hs[tb][kk];
    const float* wr = WhhT + (size_t)kk*2048;
    gi += hv*wr[k];
    gf += hv*wr[k+512];
    gg += hv*wr[k+1024];
    go += hv*wr[k+1536];
  }
  float cold = c[(size_t)b*512+k];
  float c2 = sigm_f(gf)*cold + sigm_f(gi)*tanhf(gg);
  float h2 = sigm_f(go)*tanhf(c2);
  c[(size_t)b*512+k] = c2;
  h_out[(size_t)b*512+k] = h2;
  if (ys) ys[(size_t)(b*T_STEPS + t)*512 + k] = h2;
}

// ---------------- MLP heads ----------------
// out[b][k] = act(sum_j A[b][j]*W[j][k] + bias[k]); mode 0=none,1=gelu,2=min(.,10)
__global__ void k_head(const float* __restrict__ A, const float* __restrict__ W,
                       const float* __restrict__ bias, float* __restrict__ out,
                       int K, int Nc, int mode, float* __restrict__ out2){
  int g = blockIdx.x*256 + threadIdx.x;
  if (g >= 32*Nc) return;
  int b = g / Nc, k = g % Nc;
  const float* ar = A + (size_t)b*K;
  float acc = bias[k];
  for (int j=0;j<K;++j) acc += ar[j]*W[(size_t)j*Nc+k];
  if (mode == 1) acc = gelu_f(acc);
  else if (mode == 2) acc = fminf(acc, 10.0f);
  out[g] = acc;
  if (out2) out2[g] = acc;
}

extern "C" void kernel_launch(void* const* d_in, const int* in_sizes, int n_in,
                              void* d_out, int out_size, void* d_ws, size_t ws_size,
                              hipStream_t stream){
  const float* x_seq = (const float*)d_in[0];
  const float* W1   = (const float*)d_in[1];
  const float* b1   = (const float*)d_in[2];
  const float* W2   = (const float*)d_in[3];
  const float* b2   = (const float*)d_in[4];
  const float* Wih0 = (const float*)d_in[5];
  const float* Whh0 = (const float*)d_in[6];
  const float* bih0 = (const float*)d_in[7];
  const float* bhh0 = (const float*)d_in[8];
  const float* Wih1 = (const float*)d_in[9];
  const float* Whh1 = (const float*)d_in[10];
  const float* bih1 = (const float*)d_in[11];
  const float* bhh1 = (const float*)d_in[12];
  const float* muW1 = (const float*)d_in[13];
  const float* mub1 = (const float*)d_in[14];
  const float* muW2 = (const float*)d_in[15];
  const float* mub2 = (const float*)d_in[16];
  const float* muW3 = (const float*)d_in[17];
  const float* mub3 = (const float*)d_in[18];
  const float* lvW1 = (const float*)d_in[19];
  const float* lvb1 = (const float*)d_in[20];
  const float* lvW2 = (const float*)d_in[21];
  const float* lvb2 = (const float*)d_in[22];
  const float* lvW3 = (const float*)d_in[23];
  const float* lvb3 = (const float*)d_in[24];
  const int* edge_index = (const int*)d_in[25];
  const int* batch      = (const int*)d_in[26];
  int E = in_sizes[25] / 2;
  int N = in_sizes[26];
  const int* src = edge_index;
  const int* dst = edge_index + E;
  (void)n_in; (void)out_size; (void)ws_size;

  char* w = (char*)d_ws;
  size_t off = 0;
  auto carve = [&](size_t bytes)->void*{
    void* p = w + off;
    off = (off + bytes + 255) & ~(size_t)255;
    return p;
  };

  float* dinv    = (float*)carve((size_t)N*4);
  int*   counts  = (int*)  carve((size_t)N*4);
  int*   row_ptr = (int*)  carve((size_t)(N+1)*4);
  int*   fillb   = (int*)  carve((size_t)N*4);
  int*   csr_col = (int*)  carve((size_t)E*4);
  float* ps      = (float*)carve((size_t)NB*N*4);
  float* cntb    = (float*)carve((size_t)NB*4);
  float* sx      = (float*)carve((size_t)N*256*4);
  float* h1buf   = (float*)carve((size_t)N*512*4);
  float* pp_all  = (float*)carve((size_t)T_STEPS*NB*512*4);
  float* seqb    = (float*)carve((size_t)NB*T_STEPS*512*4);
  float* WT_ih   = (float*)carve((size_t)512*2048*4);
  float* WT_hh   = (float*)carve((size_t)512*2048*4);
  float* xg      = (float*)carve((size_t)NB*T_STEPS*2048*4);
  float* ys0     = (float*)carve((size_t)NB*T_STEPS*512*4);
  float* h0b     = (float*)carve((size_t)NB*512*4);
  float* h1b     = (float*)carve((size_t)NB*512*4);
  float* cb      = (float*)carve((size_t)NB*512*4);
  float* t1      = (float*)carve((size_t)NB*512*4);
  float* t2      = (float*)carve((size_t)NB*512*4);

  hipMemsetAsync(counts, 0, (size_t)N*4, stream);
  hipMemsetAsync(fillb, 0, (size_t)N*4, stream);
  hipMemsetAsync(ps, 0, (size_t)NB*N*4, stream);
  hipMemsetAsync(cntb, 0, (size_t)NB*4, stream);
  hipMemsetAsync(pp_all, 0, (size_t)T_STEPS*NB*512*4, stream);

  int gE = (E + 255)/256, gN = (N + 255)/256;
  k_count<<<gE,256,0,stream>>>(dst, E, counts);
  k_dinv<<<gN,256,0,stream>>>(counts, dinv, N);
  k_scan<<<1,1024,0,stream>>>(counts, row_ptr, N);
  k_place<<<gE,256,0,stream>>>(src, dst, row_ptr, fillb, csr_col, E);
  k_ps_edges<<<gE,256,0,stream>>>(src, dst, batch, dinv, ps, E, N);
  k_ps_self<<<gN,256,0,stream>>>(batch, dinv, ps, cntb, N);

  dim3 gemm_grid((N+63)/64, 8);
  dim3 pool_grid((N+511)/512, 4);
  for (int t=0; t<T_STEPS; ++t){
    k_spmm<<<(N+3)/4,256,0,stream>>>(x_seq + (size_t)t*N*256, dinv, row_ptr, csr_col, sx, N);
    k_gemm_gelu<<<gemm_grid,256,0,stream>>>(sx, W1, b1, h1buf, N);
    k_pool<<<pool_grid,256,0,stream>>>(ps, h1buf, pp_all + (size_t)t*NB*512, N);
  }
  k_seq<<<(512*512)/256,256,0,stream>>>(pp_all, W2, b2, cntb, seqb);

  dim3 tr_grid(16, 64), tr_blk(32, 8);
  // LSTM layer 0
  k_transpose<<<tr_grid,tr_blk,0,stream>>>(Wih0, WT_ih, 2048, 512);
  k_transpose<<<tr_grid,tr_blk,0,stream>>>(Whh0, WT_hh, 2048, 512);
  k_xg<<<512,256,0,stream>>>(seqb, WT_ih, bih0, bhh0, xg);
  hipMemsetAsync(h0b, 0, (size_t)NB*512*4, stream);
  hipMemsetAsync(cb, 0, (size_t)NB*512*4, stream);
  for (int t=0;t<T_STEPS;++t){
    float* hin  = (t & 1) ? h1b : h0b;
    float* hout = (t & 1) ? h0b : h1b;
    k_lstm_step<<<64,256,0,stream>>>(xg, WT_hh, hin, hout, cb, ys0, t);
  }
  // LSTM layer 1
  k_transpose<<<tr_grid,tr_blk,0,stream>>>(Wih1, WT_ih, 2048, 512);
  k_transpose<<<tr_grid,tr_blk,0,stream>>>(Whh1, WT_hh, 2048, 512);
  k_xg<<<512,256,0,stream>>>(ys0, WT_ih, bih1, bhh1, xg);
  hipMemsetAsync(h0b, 0, (size_t)NB*512*4, stream);
  hipMemsetAsync(cb, 0, (size_t)NB*512*4, stream);
  for (int t=0;t<T_STEPS;++t){
    float* hin  = (t & 1) ? h1b : h0b;
    float* hout = (t & 1) ? h0b : h1b;
    k_lstm_step<<<64,256,0,stream>>>(xg, WT_hh, hin, hout, cb, (float*)nullptr, t);
  }
  float* fin = h0b;  // t=15 writes h0b

  // MLP heads: d_out = [mu(32x128), logvar(32x128), z(32x128)]
  float* mu_out = (float*)d_out;
  float* lv_out = mu_out + 32*128;
  float* z_out  = mu_out + 2*32*128;
  k_head<<<64,256,0,stream>>>(fin, muW1, mub1, t1, 512, 512, 1, (float*)nullptr);
  k_head<<<64,256,0,stream>>>(t1, muW2, mub2, t2, 512, 512, 1, (float*)nullptr);
  k_head<<<16,256,0,stream>>>(t2, muW3, mub3, mu_out, 512, 128, 0, z_out);
  k_head<<<64,256,0,stream>>>(fin, lvW1, lvb1, t1, 512, 512, 1, (float*)nullptr);
  k_head<<<64,256,0,stream>>>(t1, lvW2, lvb2, t2, 512, 512, 1, (float*)nullptr);
  k_head<<<16,256,0,stream>>>(t2, lvW3, lvb3, lv_out, 512, 128, 2, (float*)nullptr);
}

// Round 7
// 5676.988 us; speedup vs baseline: 1.1171x; 1.1171x over previous
//
#include <hip/hip_runtime.h>
#include <math.h>

#define T_STEPS 16
#define NB 32
#define D_IN 256
#define D_HID 512
#define D_LAT 128

typedef __attribute__((ext_vector_type(8))) short bf16x8_t;
typedef __attribute__((ext_vector_type(4))) float f32x4_t;

static __device__ __forceinline__ float gelu_f(float x){
  return 0.5f * x * (1.0f + erff(x * 0.70710678118654752440f));
}
static __device__ __forceinline__ float sigm_f(float x){
  return 1.0f / (1.0f + expf(-x));
}
static __device__ __forceinline__ unsigned short bf16_rn(float x){
  unsigned int u = __float_as_uint(x);
  unsigned int r = (u + 0x7FFFu + ((u >> 16) & 1u)) >> 16;
  return (unsigned short)r;
}
static __device__ __forceinline__ void split2(float x, unsigned short& hi, unsigned short& lo){
  hi = bf16_rn(x);
  float hf = __uint_as_float(((unsigned int)hi) << 16);
  lo = bf16_rn(x - hf);
}

// ---------------- precompute ----------------
__global__ void k_count(const int* __restrict__ dst, int E, int* __restrict__ counts){
  int e = blockIdx.x*256 + threadIdx.x;
  if (e < E) atomicAdd(&counts[dst[e]], 1);
}

__global__ void k_dinv(const int* __restrict__ counts, float* __restrict__ dinv, int n){
  int i = blockIdx.x*256 + threadIdx.x;
  if (i < n) dinv[i] = 1.0f / sqrtf((float)(counts[i] + 1));
}

__global__ void k_scan(const int* __restrict__ counts, int* __restrict__ row_ptr, int n){
  __shared__ int sm[1024];
  __shared__ int carry;
  if (threadIdx.x == 0) carry = 0;
  __syncthreads();
  for (int base = 0; base < n; base += 1024){
    int i = base + threadIdx.x;
    int v = (i < n) ? counts[i] : 0;
    sm[threadIdx.x] = v;
    __syncthreads();
    for (int off = 1; off < 1024; off <<= 1){
      int t = (threadIdx.x >= off) ? sm[threadIdx.x - off] : 0;
      __syncthreads();
      sm[threadIdx.x] += t;
      __syncthreads();
    }
    if (i < n) row_ptr[i] = carry + sm[threadIdx.x] - v;
    int total = sm[1023];
    __syncthreads();
    if (threadIdx.x == 0) carry += total;
    __syncthreads();
  }
  if (threadIdx.x == 0) row_ptr[n] = carry;
}

__global__ void k_place(const int* __restrict__ src, const int* __restrict__ dst,
                        const int* __restrict__ row_ptr, int* __restrict__ fill,
                        int* __restrict__ csr_col, int E){
  int e = blockIdx.x*256 + threadIdx.x;
  if (e < E){
    int d = dst[e];
    int p = row_ptr[d] + atomicAdd(&fill[d], 1);
    csr_col[p] = src[e];
  }
}

__global__ void k_ps_edges(const int* __restrict__ src, const int* __restrict__ dst,
                           const int* __restrict__ batch, const float* __restrict__ dinv,
                           float* __restrict__ ps, int E, int n){
  int e = blockIdx.x*256 + threadIdx.x;
  if (e < E){
    int s = src[e], d = dst[e];
    atomicAdd(&ps[(size_t)batch[d]*n + s], dinv[s]*dinv[d]);
  }
}

__global__ void k_ps_self(const int* __restrict__ batch, const float* __restrict__ dinv,
                          float* __restrict__ ps, float* __restrict__ cntb, int n){
  int i = blockIdx.x*256 + threadIdx.x;
  if (i < n){
    ps[(size_t)batch[i]*n + i] += dinv[i]*dinv[i];
    atomicAdd(&cntb[batch[i]], 1.0f);
  }
}

// B3T[n][0:256]=bf16hi(W1[k][n]), [256:512]=bf16lo, [512:768]=bf16hi  (n-major)
__global__ void k_prepB(const float* __restrict__ W1, unsigned short* __restrict__ B3T){
  int g = blockIdx.x*256 + threadIdx.x;      // 256*512
  if (g >= 256*512) return;
  int kc = g >> 9, n = g & 511;
  unsigned short hi, lo;
  split2(W1[(size_t)kc*512 + n], hi, lo);
  unsigned short* r = B3T + (size_t)n*768;
  r[kc] = hi; r[256+kc] = lo; r[512+kc] = hi;
}

// ---------------- GCN ----------------
// A2[i][0:256]=bf16hi(S@x_t), A2[i][256:512]=bf16lo  (row-major, 512 per row)
__global__ __launch_bounds__(256) void k_spmm(const float* __restrict__ x, const float* __restrict__ dinv,
                       const int* __restrict__ row_ptr, const int* __restrict__ csr_col,
                       unsigned short* __restrict__ A2, int n){
  int i = blockIdx.x*4 + (threadIdx.x >> 6);
  int lane = threadIdx.x & 63;
  if (i >= n) return;
  const float4* x4 = (const float4*)x;
  float di = dinv[i];
  float4 a = x4[(size_t)i*64 + lane];
  float4 acc = make_float4(di*a.x, di*a.y, di*a.z, di*a.w);
  int e0 = row_ptr[i], e1 = row_ptr[i+1];
  for (int e = e0; e < e1; ++e){
    int c = csr_col[e];
    float w = dinv[c];
    float4 v = x4[(size_t)c*64 + lane];
    acc.x += w*v.x; acc.y += w*v.y; acc.z += w*v.z; acc.w += w*v.w;
  }
  acc.x *= di; acc.y *= di; acc.z *= di; acc.w *= di;
  ushort4 h4, l4;
  split2(acc.x, h4.x, l4.x); split2(acc.y, h4.y, l4.y);
  split2(acc.z, h4.z, l4.z); split2(acc.w, h4.w, l4.w);
  *(ushort4*)(A2 + (size_t)i*512 + lane*4)       = h4;
  *(ushort4*)(A2 + (size_t)i*512 + 256 + lane*4) = l4;
}

// h1 = gelu( (Sx) @ W1 + b1 ) via 3xBF16 MFMA, K=768 segments [hi*hi | hi*lo | lo*hi]
// A2: Mp x 512 bf16 (hi|lo), B3T: 512 x 768 bf16 (n-major), C: M x 512 f32
__global__ __launch_bounds__(256) void k_gemm_mfma(const unsigned short* __restrict__ A2,
                            const unsigned short* __restrict__ B3T,
                            const float* __restrict__ bias, float* __restrict__ C, int M){
  __shared__ __align__(16) unsigned short As[128*32];  // [row][32k]
  __shared__ __align__(16) unsigned short Bs[128*32];  // [n][32k]
  int bm = blockIdx.x * 128;
  int bn = blockIdx.y * 128;
  int tid = threadIdx.x;
  int wave = tid >> 6, lane = tid & 63;
  int wr = (wave >> 1) * 64, wc = (wave & 1) * 64;
  int m16 = lane & 15, g = lane >> 4;

  f32x4_t acc[4][4];
  #pragma unroll
  for (int i=0;i<4;++i)
    #pragma unroll
    for (int j=0;j<4;++j) acc[i][j] = (f32x4_t){0.f,0.f,0.f,0.f};

  for (int s = 0; s < 24; ++s){
    int seg = s >> 3, kc = (s & 7) * 32;
    int acol = (seg == 2) ? (256 + kc) : kc;
    int bcol = s * 32;
    #pragma unroll
    for (int i = 0; i < 2; ++i){
      int c = i*256 + tid;                 // 16B chunk id
      int row = c >> 2, cb = (c & 3) * 8;  // 8 ushorts = 16B
      const unsigned short* aSrc = A2 + (size_t)(bm + row)*512 + acol + cb;
      const unsigned short* bSrc = B3T + (size_t)(bn + row)*768 + bcol + cb;
      unsigned short* aDst = (unsigned short*)As + (size_t)(i*256 + wave*64)*8;
      unsigned short* bDst = (unsigned short*)Bs + (size_t)(i*256 + wave*64)*8;
      __builtin_amdgcn_global_load_lds((const __attribute__((address_space(1))) void*)aSrc,
                                       (__attribute__((address_space(3))) void*)aDst, 16, 0, 0);
      __builtin_amdgcn_global_load_lds((const __attribute__((address_space(1))) void*)bSrc,
                                       (__attribute__((address_space(3))) void*)bDst, 16, 0, 0);
    }
    __syncthreads();
    bf16x8_t af[4], bf[4];
    #pragma unroll
    for (int f=0; f<4; ++f){
      af[f] = *(const bf16x8_t*)(As + ((wr + f*16 + m16)*32 + g*8));
      bf[f] = *(const bf16x8_t*)(Bs + ((wc + f*16 + m16)*32 + g*8));
    }
    #pragma unroll
    for (int fi=0; fi<4; ++fi)
      #pragma unroll
      for (int fj=0; fj<4; ++fj)
        acc[fi][fj] = __builtin_amdgcn_mfma_f32_16x16x32_bf16(af[fi], bf[fj], acc[fi][fj], 0, 0, 0);
    __syncthreads();
  }

  #pragma unroll
  for (int fi=0; fi<4; ++fi){
    #pragma unroll
    for (int fj=0; fj<4; ++fj){
      int col = bn + wc + fj*16 + m16;
      float bv = bias[col];
      #pragma unroll
      for (int r=0; r<4; ++r){
        int row = bm + wr + fi*16 + g*4 + r;
        if (row < M){
          float v = acc[fi][fj][r] + bv;
          C[(size_t)row*512 + col] = gelu_f(v);
        }
      }
    }
  }
}

// pp += ps(32 x n) @ h1(n x 512), split-K with atomics
__global__ __launch_bounds__(256) void k_pool(const float* __restrict__ ps, const float* __restrict__ h1,
                       float* __restrict__ pp, int n){
  __shared__ float pss[32][65];
  int tid = threadIdx.x;
  int tx = tid & 127, ty = tid >> 7;
  int k0 = blockIdx.x * 512;
  int n0 = blockIdx.y * 128;
  float acc[16];
  #pragma unroll
  for (int m=0;m<16;++m) acc[m] = 0.f;
  for (int kc=0; kc<512; kc+=64){
    int kb = k0 + kc;
    for (int s=tid; s<2048; s+=256){
      int m = s >> 6, kk = s & 63;
      int gk = kb + kk;
      pss[m][kk] = (gk < n) ? ps[(size_t)m*n + gk] : 0.f;
    }
    __syncthreads();
    int kmax = n - kb; if (kmax > 64) kmax = 64; if (kmax < 0) kmax = 0;
    for (int kk=0; kk<kmax; ++kk){
      float hv = h1[(size_t)(kb+kk)*512 + n0 + tx];
      #pragma unroll
      for (int m=0;m<16;++m) acc[m] += pss[ty*16+m][kk]*hv;
    }
    __syncthreads();
  }
  #pragma unroll
  for (int m=0;m<16;++m) atomicAdd(&pp[(size_t)(ty*16+m)*512 + n0 + tx], acc[m]);
}

// seq[b][t][k] = sum_j pp[t][b][j]*W2[j][k] + cnt[b]*b2[k]
__global__ void k_seq(const float* __restrict__ pp_all, const float* __restrict__ W2,
                      const float* __restrict__ b2, const float* __restrict__ cntb,
                      float* __restrict__ seq){
  int g = blockIdx.x*256 + threadIdx.x;  // 512*512 outputs
  int k = g & 511;
  int bt = g >> 9;
  int b = bt >> 4, t = bt & 15;
  const float* pr = pp_all + (size_t)(t*NB + b)*512;
  float acc = cntb[b]*b2[k];
  for (int j=0;j<512;++j) acc += pr[j]*W2[(size_t)j*512+k];
  seq[g] = acc;
}

// ---------------- LSTM ----------------
__global__ void k_transpose(const float* __restrict__ in, float* __restrict__ out, int R, int C){
  __shared__ float tile[32][33];
  int c0 = blockIdx.x*32, r0 = blockIdx.y*32;
  int tx = threadIdx.x, ty = threadIdx.y;  // (32,8)
  for (int j=0;j<32;j+=8){
    tile[ty+j][tx] = in[(size_t)(r0+ty+j)*C + c0 + tx];
  }
  __syncthreads();
  for (int j=0;j<32;j+=8){
    out[(size_t)(c0+ty+j)*R + r0 + tx] = tile[tx][ty+j];
  }
}

// xg[bt][j] = bih[j]+bhh[j] + sum_k in[bt][k]*WT[k][j]
__global__ __launch_bounds__(256) void k_xg(const float* __restrict__ in, const float* __restrict__ WT,
                     const float* __restrict__ bih, const float* __restrict__ bhh,
                     float* __restrict__ xg){
  __shared__ float ins[8][512];
  int jg = blockIdx.x & 7, btg = blockIdx.x >> 3;
  int tid = threadIdx.x;
  int j = jg*256 + tid;
  const float4* in4 = (const float4*)(in + (size_t)btg*8*512);
  float4* ins4 = (float4*)ins;
  for (int s=tid; s<1024; s+=256) ins4[s] = in4[s];
  __syncthreads();
  float bb = bih[j] + bhh[j];
  float acc[8];
  #pragma unroll
  for (int r=0;r<8;++r) acc[r] = bb;
  for (int kk=0; kk<512; ++kk){
    float w = WT[(size_t)kk*2048 + j];
    #pragma unroll
    for (int r=0;r<8;++r) acc[r] += ins[r][kk]*w;
  }
  for (int r=0;r<8;++r) xg[(size_t)(btg*8+r)*2048 + j] = acc[r];
}

__global__ __launch_bounds__(256) void k_lstm_step(const float* __restrict__ xg, const float* __restrict__ WhhT,
                            const float* __restrict__ h_in, float* __restrict__ h_out,
                            float* __restrict__ c, float* __restrict__ ys, int t){
  __shared__ float hs[8][512];
  int kg = blockIdx.x & 15, bg = blockIdx.x >> 4;
  int tid = threadIdx.x;
  int tb = tid >> 5, tk = tid & 31;
  const float4* h4 = (const float4*)(h_in + (size_t)bg*8*512);
  float4* hs4 = (float4*)hs;
  for (int s=tid; s<1024; s+=256) hs4[s] = h4[s];
  __syncthreads();
  int b = bg*8 + tb;
  int k = kg*32 + tk;
  const float* xgr = xg + (size_t)(b*T_STEPS + t)*2048;
  float gi = xgr[k], gf = xgr[k+512], gg = xgr[k+1024], go = xgr[k+1536];
  for (int kk=0; kk<512; ++kk){
    float hv = hs[tb][kk];
    const float* wr = WhhT + (size_t)kk*2048;
    gi += hv*wr[k];
    gf += hv*wr[k+512];
    gg += hv*wr[k+1024];
    go += hv*wr[k+1536];
  }
  float cold = c[(size_t)b*512+k];
  float c2 = sigm_f(gf)*cold + sigm_f(gi)*tanhf(gg);
  float h2 = sigm_f(go)*tanhf(c2);
  c[(size_t)b*512+k] = c2;
  h_out[(size_t)b*512+k] = h2;
  if (ys) ys[(size_t)(b*T_STEPS + t)*512 + k] = h2;
}

// ---------------- MLP heads ----------------
__global__ void k_head(const float* __restrict__ A, const float* __restrict__ W,
                       const float* __restrict__ bias, float* __restrict__ out,
                       int K, int Nc, int mode, float* __restrict__ out2){
  int g = blockIdx.x*256 + threadIdx.x;
  if (g >= 32*Nc) return;
  int b = g / Nc, k = g % Nc;
  const float* ar = A + (size_t)b*K;
  float acc = bias[k];
  for (int j=0;j<K;++j) acc += ar[j]*W[(size_t)j*Nc+k];
  if (mode == 1) acc = gelu_f(acc);
  else if (mode == 2) acc = fminf(acc, 10.0f);
  out[g] = acc;
  if (out2) out2[g] = acc;
}

extern "C" void kernel_launch(void* const* d_in, const int* in_sizes, int n_in,
                              void* d_out, int out_size, void* d_ws, size_t ws_size,
                              hipStream_t stream){
  const float* x_seq = (const float*)d_in[0];
  const float* W1   = (const float*)d_in[1];
  const float* b1   = (const float*)d_in[2];
  const float* W2   = (const float*)d_in[3];
  const float* b2   = (const float*)d_in[4];
  const float* Wih0 = (const float*)d_in[5];
  const float* Whh0 = (const float*)d_in[6];
  const float* bih0 = (const float*)d_in[7];
  const float* bhh0 = (const float*)d_in[8];
  const float* Wih1 = (const float*)d_in[9];
  const float* Whh1 = (const float*)d_in[10];
  const float* bih1 = (const float*)d_in[11];
  const float* bhh1 = (const float*)d_in[12];
  const float* muW1 = (const float*)d_in[13];
  const float* mub1 = (const float*)d_in[14];
  const float* muW2 = (const float*)d_in[15];
  const float* mub2 = (const float*)d_in[16];
  const float* muW3 = (const float*)d_in[17];
  const float* mub3 = (const float*)d_in[18];
  const float* lvW1 = (const float*)d_in[19];
  const float* lvb1 = (const float*)d_in[20];
  const float* lvW2 = (const float*)d_in[21];
  const float* lvb2 = (const float*)d_in[22];
  const float* lvW3 = (const float*)d_in[23];
  const float* lvb3 = (const float*)d_in[24];
  const int* edge_index = (const int*)d_in[25];
  const int* batch      = (const int*)d_in[26];
  int E = in_sizes[25] / 2;
  int N = in_sizes[26];
  const int* src = edge_index;
  const int* dst = edge_index + E;
  (void)n_in; (void)out_size; (void)ws_size;

  int Mp = ((N + 127) & ~127);  // padded rows for GEMM tiles (20096)

  char* w = (char*)d_ws;
  size_t off = 0;
  auto carve = [&](size_t bytes)->void*{
    void* p = w + off;
    off = (off + bytes + 255) & ~(size_t)255;
    return p;
  };

  float* dinv    = (float*)carve((size_t)N*4);
  int*   counts  = (int*)  carve((size_t)N*4);
  int*   row_ptr = (int*)  carve((size_t)(N+1)*4);
  int*   fillb   = (int*)  carve((size_t)N*4);
  int*   csr_col = (int*)  carve((size_t)E*4);
  float* ps      = (float*)carve((size_t)NB*N*4);
  float* cntb    = (float*)carve((size_t)NB*4);
  unsigned short* A2  = (unsigned short*)carve((size_t)Mp*512*2);
  unsigned short* B3T = (unsigned short*)carve((size_t)512*768*2);
  float* h1buf   = (float*)carve((size_t)N*512*4);
  float* pp_all  = (float*)carve((size_t)T_STEPS*NB*512*4);
  float* seqb    = (float*)carve((size_t)NB*T_STEPS*512*4);
  float* WT_ih   = (float*)carve((size_t)512*2048*4);
  float* WT_hh   = (float*)carve((size_t)512*2048*4);
  float* xg      = (float*)carve((size_t)NB*T_STEPS*2048*4);
  float* ys0     = (float*)carve((size_t)NB*T_STEPS*512*4);
  float* h0b     = (float*)carve((size_t)NB*512*4);
  float* h1b     = (float*)carve((size_t)NB*512*4);
  float* cb      = (float*)carve((size_t)NB*512*4);
  float* t1      = (float*)carve((size_t)NB*512*4);
  float* t2      = (float*)carve((size_t)NB*512*4);

  hipMemsetAsync(counts, 0, (size_t)N*4, stream);
  hipMemsetAsync(fillb, 0, (size_t)N*4, stream);
  hipMemsetAsync(ps, 0, (size_t)NB*N*4, stream);
  hipMemsetAsync(cntb, 0, (size_t)NB*4, stream);
  hipMemsetAsync(pp_all, 0, (size_t)T_STEPS*NB*512*4, stream);
  // zero A2 pad rows (N..Mp) so tail GEMM tiles see zeros, not ws poison
  hipMemsetAsync(A2 + (size_t)N*512, 0, (size_t)(Mp - N)*512*2, stream);

  int gE = (E + 255)/256, gN = (N + 255)/256;
  k_count<<<gE,256,0,stream>>>(dst, E, counts);
  k_dinv<<<gN,256,0,stream>>>(counts, dinv, N);
  k_scan<<<1,1024,0,stream>>>(counts, row_ptr, N);
  k_place<<<gE,256,0,stream>>>(src, dst, row_ptr, fillb, csr_col, E);
  k_ps_edges<<<gE,256,0,stream>>>(src, dst, batch, dinv, ps, E, N);
  k_ps_self<<<gN,256,0,stream>>>(batch, dinv, ps, cntb, N);
  k_prepB<<<512,256,0,stream>>>(W1, B3T);

  dim3 gemm_grid(Mp/128, 4);
  dim3 pool_grid((N+511)/512, 4);
  for (int t=0; t<T_STEPS; ++t){
    k_spmm<<<(N+3)/4,256,0,stream>>>(x_seq + (size_t)t*N*256, dinv, row_ptr, csr_col, A2, N);
    k_gemm_mfma<<<gemm_grid,256,0,stream>>>(A2, B3T, b1, h1buf, N);
    k_pool<<<pool_grid,256,0,stream>>>(ps, h1buf, pp_all + (size_t)t*NB*512, N);
  }
  k_seq<<<(512*512)/256,256,0,stream>>>(pp_all, W2, b2, cntb, seqb);

  dim3 tr_grid(16, 64), tr_blk(32, 8);
  // LSTM layer 0
  k_transpose<<<tr_grid,tr_blk,0,stream>>>(Wih0, WT_ih, 2048, 512);
  k_transpose<<<tr_grid,tr_blk,0,stream>>>(Whh0, WT_hh, 2048, 512);
  k_xg<<<512,256,0,stream>>>(seqb, WT_ih, bih0, bhh0, xg);
  hipMemsetAsync(h0b, 0, (size_t)NB*512*4, stream);
  hipMemsetAsync(cb, 0, (size_t)NB*512*4, stream);
  for (int t=0;t<T_STEPS;++t){
    float* hin  = (t & 1) ? h1b : h0b;
    float* hout = (t & 1) ? h0b : h1b;
    k_lstm_step<<<64,256,0,stream>>>(xg, WT_hh, hin, hout, cb, ys0, t);
  }
  // LSTM layer 1
  k_transpose<<<tr_grid,tr_blk,0,stream>>>(Wih1, WT_ih, 2048, 512);
  k_transpose<<<tr_grid,tr_blk,0,stream>>>(Whh1, WT_hh, 2048, 512);
  k_xg<<<512,256,0,stream>>>(ys0, WT_ih, bih1, bhh1, xg);
  hipMemsetAsync(h0b, 0, (size_t)NB*512*4, stream);
  hipMemsetAsync(cb, 0, (size_t)NB*512*4, stream);
  for (int t=0;t<T_STEPS;++t){
    float* hin  = (t & 1) ? h1b : h0b;
    float* hout = (t & 1) ? h0b : h1b;
    k_lstm_step<<<64,256,0,stream>>>(xg, WT_hh, hin, hout, cb, (float*)nullptr, t);
  }
  float* fin = h0b;  // t=15 writes h0b

  // MLP heads: d_out = [mu(32x128), logvar(32x128), z(32x128)]
  float* mu_out = (float*)d_out;
  float* lv_out = mu_out + 32*128;
  float* z_out  = mu_out + 2*32*128;
  k_head<<<64,256,0,stream>>>(fin, muW1, mub1, t1, 512, 512, 1, (float*)nullptr);
  k_head<<<64,256,0,stream>>>(t1, muW2, mub2, t2, 512, 512, 1, (float*)nullptr);
  k_head<<<16,256,0,stream>>>(t2, muW3, mub3, mu_out, 512, 128, 0, z_out);
  k_head<<<64,256,0,stream>>>(fin, lvW1, lvb1, t1, 512, 512, 1, (float*)nullptr);
  k_head<<<64,256,0,stream>>>(t1, lvW2, lvb2, t2, 512, 512, 1, (float*)nullptr);
  k_head<<<16,256,0,stream>>>(t2, lvW3, lvb3, lv_out, 512, 128, 2, (float*)nullptr);
}